// Round 4
// baseline (455.642 us; speedup 1.0000x reference)
//
#include <hip/hip_runtime.h>

#define WS 9
#define PS 7
#define KMAX 10
#define STRIDE0 4
#define NEPOCHS 100
#define BB 1
#define TT 5
#define CC 3
#define HH 256
#define WW 256
#define NH 64
#define NW 64
#define QQ (TT * NH * NW)             // 20480
#define NOFF 243
#define SELF_IDX 40                   // (WS/2)*WS + WS/2
#define HW (HH * WW)

typedef float f4u __attribute__((ext_vector_type(4), aligned(4)));
typedef float f2u __attribute__((ext_vector_type(2), aligned(4)));

static __device__ __forceinline__ int k_eff_from_epoch(int ep) {
    int k = (int)((double)KMAX * ((double)(NEPOCHS - ep) / (double)NEPOCHS));
    return k < 2 ? 2 : k;
}

// One wave (64 lanes) per query; 4 queries per 256-thread block; no tile LDS.
// Search: 27 groups (dti,dh) x 8 lanes (sub = patch row i; sub==7 idle).
// Each lane reads its 15-float candidate row + 7-float query row from L2 and
// computes 9 dw candidates; shfl_xor tree over the 8-lane segment sums rows.
__global__ __launch_bounds__(256) void dnls_query_kernel(
    const float* __restrict__ noisy, const float* __restrict__ deno,
    const float* __restrict__ fflow, const float* __restrict__ bflow,
    const int* __restrict__ ep_ptr, float* __restrict__ partial)
{
    const int wid  = threadIdx.x >> 6;
    const int lane = threadIdx.x & 63;
    const int q    = blockIdx.x * 4 + wid;     // 0..20479
    const int tqi  = q >> 12;                  // / (NH*NW)
    const int r0   = q & 4095;
    const int hq   = (r0 >> 6) * STRIDE0;
    const int wq   = (r0 & 63) * STRIDE0;
    const int k_eff = k_eff_from_epoch(ep_ptr[0]);

    __shared__ float dists[4][256];
    float* dq = dists[wid];

    // --- centers (redundant per lane; flow loads are wave-broadcast) ---
    const size_t bf = (size_t)(tqi * 2) * HW + (size_t)hq * WW + wq;
    const int ifdx = (int)rintf(fflow[bf]);
    const int ifdy = (int)rintf(fflow[bf + HW]);
    const int ibdx = (int)rintf(bflow[bf]);
    const int ibdy = (int)rintf(bflow[bf + HW]);
    const int tc0 = tqi, tc1 = max(tqi - 1, 0), tc2 = min(tqi + 1, TT - 1);
    const int hv0 = hq, hv1 = min(max(hq + ibdy, 0), HH - 1), hv2 = min(max(hq + ifdy, 0), HH - 1);
    const int wv0 = wq, wv1 = min(max(wq + ibdx, 0), WW - 1), wv2 = min(max(wq + ifdx, 0), WW - 1);

    for (int r = 0; r < 4; ++r) {
        const int s = r * 64 + lane;
        const int g = s >> 3, sub = s & 7;
        if (g < 27) {
            const int dti = g / 9, dh = g - dti * 9;
            const int tc  = dti == 0 ? tc0 : (dti == 1 ? tc1 : tc2);
            const int hcv = dti == 0 ? hv0 : (dti == 1 ? hv1 : hv2);
            const int wcv = dti == 0 ? wv0 : (dti == 1 ? wv1 : wv2);
            float acc[9];
            #pragma unroll
            for (int dw = 0; dw < 9; ++dw) acc[dw] = 0.f;
            if (sub < PS) {
                const int i    = sub;
                const int hc   = min(max(hcv + dh - 4, 0), HH - 1);  // candidate center row (clamped)
                const int rowh = min(hc + i, HH - 1);                // patch row (second clamp)
                const int rowq = min(hq + i, HH - 1);
                const float* tbase = noisy + (size_t)(tc  * CC) * HW + (size_t)rowh * WW;
                const float* qbase = noisy + (size_t)(tqi * CC) * HW + (size_t)rowq * WW;
                if (wcv >= 4 && wcv <= WW - 11 && wq <= WW - 8) {
                    // fast path: cols = (wcv-4)+dw+j, all in-bounds, no clamps
                    const int w0 = wcv - 4;
                    #pragma unroll
                    for (int c = 0; c < CC; ++c) {
                        const float* trow = tbase + c * HW + w0;
                        const float* qrow = qbase + c * HW + wq;
                        float tv[15], qv[7];
                        *(f4u*)&tv[0]  = *(const f4u*)(trow);
                        *(f4u*)&tv[4]  = *(const f4u*)(trow + 4);
                        *(f4u*)&tv[8]  = *(const f4u*)(trow + 8);
                        *(f2u*)&tv[12] = *(const f2u*)(trow + 12);
                        tv[14] = trow[14];
                        *(f4u*)&qv[0] = *(const f4u*)(qrow);
                        *(f2u*)&qv[4] = *(const f2u*)(qrow + 4);
                        qv[6] = qrow[6];
                        #pragma unroll
                        for (int dw = 0; dw < 9; ++dw) {
                            #pragma unroll
                            for (int j = 0; j < 7; ++j) {
                                const float d = qv[j] - tv[dw + j];
                                acc[dw] = fmaf(d, d, acc[dw]);
                            }
                        }
                    }
                } else {
                    // edge path: double clamp (center, then +j), scalar L2 reads
                    const int w0 = wcv - 4;
                    #pragma unroll
                    for (int c = 0; c < CC; ++c) {
                        const float* trow = tbase + c * HW;
                        const float* qrow = qbase + c * HW;
                        float qv[7];
                        #pragma unroll
                        for (int j = 0; j < 7; ++j)
                            qv[j] = qrow[min(wq + j, WW - 1)];
                        #pragma unroll
                        for (int dw = 0; dw < 9; ++dw) {
                            const int wc = min(max(w0 + dw, 0), WW - 1);
                            #pragma unroll
                            for (int j = 0; j < 7; ++j) {
                                const float d = qv[j] - trow[min(wc + j, WW - 1)];
                                acc[dw] = fmaf(d, d, acc[dw]);
                            }
                        }
                    }
                }
            }
            // tree-sum the 7 patch rows across the 8-lane segment
            #pragma unroll
            for (int dw = 0; dw < 9; ++dw) {
                float v = acc[dw];
                v += __shfl_xor(v, 1);
                v += __shfl_xor(v, 2);
                v += __shfl_xor(v, 4);
                acc[dw] = v;
            }
            if (sub == 0) {
                #pragma unroll
                for (int dw = 0; dw < 9; ++dw) dq[g * 9 + dw] = acc[dw];
            }
        }
    }
    __syncthreads();   // order dist writes -> reads (also cheap cross-wave align)

    // --- wave-local in-register top-k (strict <, lowest-index tie-break) ---
    float dv[4]; int dn[4];
    #pragma unroll
    for (int kk = 0; kk < 4; ++kk) {
        const int n = lane + kk * 64;
        float v = (n < NOFF) ? dq[n] : INFINITY;
        if (n == SELF_IDX) v = -INFINITY;      // anchor self to slot 0
        dv[kk] = v; dn[kk] = n;
    }
    int seln[KMAX];
    #pragma unroll
    for (int k = 0; k < KMAX; ++k) {
        float bv = dv[0]; int bi = dn[0];
        #pragma unroll
        for (int kk = 1; kk < 4; ++kk)
            if (dv[kk] < bv || (dv[kk] == bv && dn[kk] < bi)) { bv = dv[kk]; bi = dn[kk]; }
        #pragma unroll
        for (int off = 32; off > 0; off >>= 1) {
            const float ov = __shfl_xor(bv, off);
            const int   oi = __shfl_xor(bi, off);
            if (ov < bv || (ov == bv && oi < bi)) { bv = ov; bi = oi; }
        }
        seln[k] = bi;                          // identical in all lanes
        #pragma unroll
        for (int kk = 0; kk < 4; ++kk) if (dn[kk] == bi) dv[kk] = INFINITY;
    }

    // --- refine: deno-query vs noisy at selected positions (slots 1..k_eff-1) ---
    float part = 0.f;
    const int nref = (k_eff - 1) * 49;
    for (int u = lane; u < nref; u += 64) {
        const int kk = u / 49 + 1;
        const int ij = u - (kk - 1) * 49;
        const int i = ij / 7, j = ij - (ij / 7) * 7;
        int n = seln[1];
        #pragma unroll
        for (int t = 2; t < KMAX; ++t) if (kk == t) n = seln[t];  // const-indexed select
        const int dti = n / 81;
        const int rr  = n - dti * 81;
        const int dh  = rr / 9;
        const int dw  = rr - dh * 9;
        const int tc  = dti == 0 ? tc0 : (dti == 1 ? tc1 : tc2);
        const int hcv = dti == 0 ? hv0 : (dti == 1 ? hv1 : hv2);
        const int wcv = dti == 0 ? wv0 : (dti == 1 ? wv1 : wv2);
        const int hc  = min(max(hcv + dh - 4, 0), HH - 1);
        const int wc  = min(max(wcv + dw - 4, 0), WW - 1);
        const int row  = min(hc + i, HH - 1);
        const int col  = min(wc + j, WW - 1);
        const int rowq = min(hq + i, HH - 1);
        const int colq = min(wq + j, WW - 1);
        const float* nb = noisy + (size_t)(tc  * CC) * HW + (size_t)row  * WW + col;
        const float* db = deno  + (size_t)(tqi * CC) * HW + (size_t)rowq * WW + colq;
        #pragma unroll
        for (int c = 0; c < CC; ++c) {
            const float d = db[c * HW] - nb[c * HW];
            part = fmaf(d, d, part);
        }
    }

    #pragma unroll
    for (int off = 32; off > 0; off >>= 1) part += __shfl_xor(part, off);
    if (lane == 0) partial[q] = part;
}

__global__ __launch_bounds__(1024) void dnls_reduce_kernel(
    const float* __restrict__ partial, int n,
    const int* __restrict__ ep_ptr, float* __restrict__ out)
{
    const int tid = threadIdx.x;
    double acc = 0.0;
    for (int i = tid; i < n; i += 1024) acc += (double)partial[i];
    __shared__ double red[1024];
    red[tid] = acc;
    __syncthreads();
    for (int s = 512; s > 0; s >>= 1) {
        if (tid < s) red[tid] += red[tid + s];
        __syncthreads();
    }
    if (tid == 0) {
        const int k_eff = k_eff_from_epoch(ep_ptr[0]);
        out[0] = (float)(red[0] / ((double)n * (double)(k_eff - 1)));
    }
}

extern "C" void kernel_launch(void* const* d_in, const int* in_sizes, int n_in,
                              void* d_out, int out_size, void* d_ws, size_t ws_size,
                              hipStream_t stream) {
    const float* noisy = (const float*)d_in[0];
    const float* deno  = (const float*)d_in[1];
    const float* fflow = (const float*)d_in[2];
    const float* bflow = (const float*)d_in[3];
    const int*   ep    = (const int*)d_in[4];
    float* partial = (float*)d_ws;            // BB*QQ floats = 80 KB
    float* out = (float*)d_out;

    dnls_query_kernel<<<(BB * QQ) / 4, 256, 0, stream>>>(noisy, deno, fflow, bflow, ep, partial);
    dnls_reduce_kernel<<<1, 1024, 0, stream>>>(partial, BB * QQ, ep, out);
}

// Round 5
// 239.180 us; speedup vs baseline: 1.9050x; 1.9050x over previous
//
#include <hip/hip_runtime.h>

#define WS 9
#define PS 7
#define KMAX 10
#define STRIDE0 4
#define NEPOCHS 100
#define BB 1
#define TT 5
#define CC 3
#define HH 256
#define WW 256
#define NH 64
#define NW 64
#define QQ (TT * NH * NW)             // 20480
#define NOFF 243
#define SELF_IDX 40                   // (WS/2)*WS + WS/2
#define HW (HH * WW)
#define TSTR 20                       // tile row stride: 80B = b128-aligned, 8 rows -> 8 bank-quads

typedef float f4a __attribute__((ext_vector_type(4)));

static __device__ __forceinline__ int k_eff_from_epoch(int ep) {
    int k = (int)((double)KMAX * ((double)(NEPOCHS - ep) / (double)NEPOCHS));
    return k < 2 ? 2 : k;
}

// One query per 256-thread block. LDS tile per (dti,channel): 15 rows x 15 cols
// (stride 20), clamps materialized at staging. Search: 27 groups (dti,dh) x 8
// lanes (sub = patch row i), vector LDS reads + register sliding window over 9
// dw; shfl_xor tree sums rows. Top-k in registers (wave-redundant). Refine from
// LDS. 3 barriers total.
__global__ __launch_bounds__(256) void dnls_query_kernel(
    const float* __restrict__ noisy, const float* __restrict__ deno,
    const float* __restrict__ fflow, const float* __restrict__ bflow,
    const int* __restrict__ ep_ptr, float* __restrict__ partial)
{
    const int q    = blockIdx.x;
    const int tqi  = q >> 12;
    const int r0   = q & 4095;
    const int hq   = (r0 >> 6) * STRIDE0;
    const int wq   = (r0 & 63) * STRIDE0;
    const int tid  = threadIdx.x;
    const int lane = tid & 63;
    const int k_eff = k_eff_from_epoch(ep_ptr[0]);

    __shared__ float tile[3][CC][15][TSTR];   // 10.8 KB
    __shared__ float qpat[CC][PS][8];         // noisy query patch (rows b128-aligned)
    __shared__ float dpat[CC][PS][8];         // deno query patch
    __shared__ float dists[256];
    __shared__ float redbuf[4];

    // --- centers (every thread; flow loads are wave-uniform -> broadcast) ---
    const size_t bfo = (size_t)(tqi * 2) * HW + (size_t)hq * WW + wq;
    const int ifdx = (int)rintf(fflow[bfo]);
    const int ifdy = (int)rintf(fflow[bfo + HW]);
    const int ibdx = (int)rintf(bflow[bfo]);
    const int ibdy = (int)rintf(bflow[bfo + HW]);
    const int tcA[3] = { tqi, max(tqi - 1, 0), min(tqi + 1, TT - 1) };
    const int hvA[3] = { hq, min(max(hq + ibdy, 0), HH - 1), min(max(hq + ifdy, 0), HH - 1) };
    const int wvA[3] = { wq, min(max(wq + ibdx, 0), WW - 1), min(max(wq + ifdx, 0), WW - 1) };

    // --- stage tiles: 9 unrolled (dti,c) planes, 225 elems each, clamps baked in ---
    #pragma unroll
    for (int dtc = 0; dtc < 9; ++dtc) {
        const int dti = dtc / 3, c = dtc % 3;          // compile-time
        if (tid < 225) {
            const int row = tid / 15;
            const int col = tid - row * 15;
            const int h0 = max(hvA[dti] - 4, 0);
            const int w0 = max(wvA[dti] - 4, 0);
            const float* src = noisy + (size_t)(tcA[dti] * CC + c) * HW;
            tile[dti][c][row][col] = src[min(h0 + row, HH - 1) * WW + min(w0 + col, WW - 1)];
        }
    }
    // --- stage query patches (clamps baked in) ---
    if (tid < CC * PS * PS) {
        const int c = tid / 49, ij = tid - c * 49, i = ij / 7, j = ij - (ij / 7) * 7;
        const size_t idx = (size_t)(tqi * CC + c) * HW + min(hq + i, HH - 1) * WW + min(wq + j, WW - 1);
        qpat[c][i][j] = noisy[idx];
        dpat[c][i][j] = deno[idx];
    }
    __syncthreads();

    // --- search: group g=(dti,dh), sub = patch row i (sub==7 idle) ---
    {
        const int g = tid >> 3, sub = tid & 7;
        if (g < 27) {
            const int dti = (g >= 18) ? 2 : (g >= 9 ? 1 : 0);
            const int dh  = g - 9 * dti;
            const int hcv = hvA[dti], wcv = wvA[dti];
            float acc[9];
            #pragma unroll
            for (int dw = 0; dw < 9; ++dw) acc[dw] = 0.f;
            if (sub < PS) {
                const int i = sub;
                if (hcv >= 4 && wcv >= 4) {
                    // fast path: staged clamps are exact; r = dh+i, cols = dw+j
                    const int r = dh + i;
                    #pragma unroll
                    for (int c = 0; c < CC; ++c) {
                        float qv[8], tv[16];
                        *(f4a*)&qv[0]  = *(const f4a*)&qpat[c][i][0];
                        *(f4a*)&qv[4]  = *(const f4a*)&qpat[c][i][4];
                        *(f4a*)&tv[0]  = *(const f4a*)&tile[dti][c][r][0];
                        *(f4a*)&tv[4]  = *(const f4a*)&tile[dti][c][r][4];
                        *(f4a*)&tv[8]  = *(const f4a*)&tile[dti][c][r][8];
                        *(f4a*)&tv[12] = *(const f4a*)&tile[dti][c][r][12];
                        #pragma unroll
                        for (int dw = 0; dw < 9; ++dw) {
                            #pragma unroll
                            for (int j = 0; j < 7; ++j) {
                                const float d = qv[j] - tv[dw + j];
                                acc[dw] = fmaf(d, d, acc[dw]);
                            }
                        }
                    }
                } else {
                    // top/left-edge centers: double clamp mapped into the tile
                    const int h0 = max(hcv - 4, 0), w0 = max(wcv - 4, 0);
                    const int hc = min(max(hcv + dh - 4, 0), HH - 1);
                    const int r  = min(hc + i, HH - 1) - h0;
                    #pragma unroll
                    for (int c = 0; c < CC; ++c) {
                        float qv[8];
                        *(f4a*)&qv[0] = *(const f4a*)&qpat[c][i][0];
                        *(f4a*)&qv[4] = *(const f4a*)&qpat[c][i][4];
                        #pragma unroll
                        for (int dw = 0; dw < 9; ++dw) {
                            const int wc = min(max(wcv + dw - 4, 0), WW - 1);
                            #pragma unroll
                            for (int j = 0; j < 7; ++j) {
                                const int col = min(wc + j, WW - 1) - w0;
                                const float d = qv[j] - tile[dti][c][r][col];
                                acc[dw] = fmaf(d, d, acc[dw]);
                            }
                        }
                    }
                }
            }
            // sum the 7 rows across the 8-lane segment
            #pragma unroll
            for (int dw = 0; dw < 9; ++dw) {
                float v = acc[dw];
                v += __shfl_xor(v, 1);
                v += __shfl_xor(v, 2);
                v += __shfl_xor(v, 4);
                acc[dw] = v;
            }
            if (sub == 0) {
                #pragma unroll
                for (int dw = 0; dw < 9; ++dw) dists[g * 9 + dw] = acc[dw];
            }
        }
    }
    __syncthreads();

    // --- in-register top-k, wave-redundant (strict <, lowest-index tie-break) ---
    float dv[4]; int dn[4];
    #pragma unroll
    for (int kk = 0; kk < 4; ++kk) {
        const int n = lane + kk * 64;
        float v = (n < NOFF) ? dists[n] : INFINITY;
        if (n == SELF_IDX) v = -INFINITY;
        dv[kk] = v; dn[kk] = n;
    }
    int seln[KMAX];
    #pragma unroll
    for (int k = 0; k < KMAX; ++k) {
        float bv = dv[0]; int bi = dn[0];
        #pragma unroll
        for (int kk = 1; kk < 4; ++kk)
            if (dv[kk] < bv || (dv[kk] == bv && dn[kk] < bi)) { bv = dv[kk]; bi = dn[kk]; }
        #pragma unroll
        for (int off = 32; off > 0; off >>= 1) {
            const float ov = __shfl_xor(bv, off);
            const int   oi = __shfl_xor(bi, off);
            if (ov < bv || (ov == bv && oi < bi)) { bv = ov; bi = oi; }
        }
        seln[k] = bi;
        #pragma unroll
        for (int kk = 0; kk < 4; ++kk) if (dn[kk] == bi) dv[kk] = INFINITY;
    }

    // --- refine: deno-query vs noisy at selected positions (slots 1..k_eff-1) ---
    float part = 0.f;
    const int nref = (k_eff - 1) * 49;
    for (int u = tid; u < nref; u += 256) {
        const int kk = u / 49 + 1;
        const int ij = u - (kk - 1) * 49;
        const int i = ij / 7, j = ij - (ij / 7) * 7;
        int n = seln[1];
        #pragma unroll
        for (int t = 2; t < KMAX; ++t) if (kk == t) n = seln[t];
        const int dti = (n >= 162) ? 2 : (n >= 81 ? 1 : 0);
        const int rr  = n - dti * 81;
        const int dh  = rr / 9;
        const int dw  = rr - dh * 9;
        const int hcv = hvA[dti], wcv = wvA[dti];
        const int h0  = max(hcv - 4, 0), w0 = max(wcv - 4, 0);
        const int hc  = min(max(hcv + dh - 4, 0), HH - 1);
        const int wc  = min(max(wcv + dw - 4, 0), WW - 1);
        const int row = min(hc + i, HH - 1) - h0;
        const int col = min(wc + j, WW - 1) - w0;
        #pragma unroll
        for (int c = 0; c < CC; ++c) {
            const float d = dpat[c][i][j] - tile[dti][c][row][col];
            part = fmaf(d, d, part);
        }
    }

    #pragma unroll
    for (int off = 32; off > 0; off >>= 1) part += __shfl_xor(part, off);
    if (lane == 0) redbuf[tid >> 6] = part;
    __syncthreads();
    if (tid == 0) partial[q] = redbuf[0] + redbuf[1] + redbuf[2] + redbuf[3];
}

__global__ __launch_bounds__(1024) void dnls_reduce_kernel(
    const float* __restrict__ partial, int n,
    const int* __restrict__ ep_ptr, float* __restrict__ out)
{
    const int tid = threadIdx.x;
    double acc = 0.0;
    for (int i = tid; i < n; i += 1024) acc += (double)partial[i];
    __shared__ double red[1024];
    red[tid] = acc;
    __syncthreads();
    for (int s = 512; s > 0; s >>= 1) {
        if (tid < s) red[tid] += red[tid + s];
        __syncthreads();
    }
    if (tid == 0) {
        const int k_eff = k_eff_from_epoch(ep_ptr[0]);
        out[0] = (float)(red[0] / ((double)n * (double)(k_eff - 1)));
    }
}

extern "C" void kernel_launch(void* const* d_in, const int* in_sizes, int n_in,
                              void* d_out, int out_size, void* d_ws, size_t ws_size,
                              hipStream_t stream) {
    const float* noisy = (const float*)d_in[0];
    const float* deno  = (const float*)d_in[1];
    const float* fflow = (const float*)d_in[2];
    const float* bflow = (const float*)d_in[3];
    const int*   ep    = (const int*)d_in[4];
    float* partial = (float*)d_ws;            // BB*QQ floats = 80 KB
    float* out = (float*)d_out;

    dnls_query_kernel<<<BB * QQ, 256, 0, stream>>>(noisy, deno, fflow, bflow, ep, partial);
    dnls_reduce_kernel<<<1, 1024, 0, stream>>>(partial, BB * QQ, ep, out);
}

// Round 6
// 229.709 us; speedup vs baseline: 1.9836x; 1.0412x over previous
//
#include <hip/hip_runtime.h>

#define WS 9
#define PS 7
#define KMAX 10
#define STRIDE0 4
#define NEPOCHS 100
#define BB 1
#define TT 5
#define CC 3
#define HH 256
#define WW 256
#define QQ (TT * 64 * 64)             // 20480
#define NOFF 243
#define SELF_IDX 40                   // (WS/2)*WS + WS/2
#define HW (HH * WW)
#define TSW(r) (((r) & 3) << 2)       // XOR bank swizzle for 16-float rows

typedef float f4a __attribute__((ext_vector_type(4)));                 // 16B-aligned LDS
typedef float f4u __attribute__((ext_vector_type(4), aligned(4)));     // unaligned global

static __device__ __forceinline__ int k_eff_from_epoch(int ep) {
    int k = (int)((double)KMAX * ((double)(NEPOCHS - ep) / (double)NEPOCHS));
    return k < 2 ? 2 : k;
}

// One WAVE per query; 4 independent queries per 256-thread block; no __syncthreads.
// Tile: [dti][c][15 rows][16 cols] per query, col XOR-swizzled by row for
// conflict-free b128 reads. Search: 4 iterations x 8 groups (dti,dh) x 8 lanes
// (sub = patch row i, sub==7 contributes 0); query row held in registers from
// global. Top-k once per wave in registers. Refine: tile LDS + deno from global.
__global__ __launch_bounds__(256, 4) void dnls_query_kernel(
    const float* __restrict__ noisy, const float* __restrict__ deno,
    const float* __restrict__ fflow, const float* __restrict__ bflow,
    const int* __restrict__ ep_ptr, float* __restrict__ partial)
{
    const int wid  = threadIdx.x >> 6;
    const int lane = threadIdx.x & 63;
    const int q    = blockIdx.x * 4 + wid;
    const int tqi  = q >> 12;
    const int r0   = q & 4095;
    const int hq   = (r0 >> 6) * STRIDE0;
    const int wq   = (r0 & 63) * STRIDE0;
    const int sub  = lane & 7;          // patch row i (7 => idle in compute)
    const int k_eff = k_eff_from_epoch(ep_ptr[0]);

    __shared__ float tile[4][3][CC][15][16];   // 34.6 KB: per-wave search windows
    __shared__ float dists[4][256];            // 4 KB: per-wave candidate dists

    // --- centers (wave-uniform) ---
    const size_t bfo = (size_t)(tqi * 2) * HW + (size_t)hq * WW + wq;
    const int ifdx = (int)rintf(fflow[bfo]);
    const int ifdy = (int)rintf(fflow[bfo + HW]);
    const int ibdx = (int)rintf(bflow[bfo]);
    const int ibdy = (int)rintf(bflow[bfo + HW]);
    const int tc0 = tqi, tc1 = max(tqi - 1, 0), tc2 = min(tqi + 1, TT - 1);
    const int hv0 = hq, hv1 = min(max(hq + ibdy, 0), HH - 1), hv2 = min(max(hq + ifdy, 0), HH - 1);
    const int wv0 = wq, wv1 = min(max(wq + ibdx, 0), WW - 1), wv2 = min(max(wq + ifdx, 0), WW - 1);

    // --- stage tiles (this wave only): storage[p] = logical[p ^ TSW(row)] ---
    #pragma unroll
    for (int dti = 0; dti < 3; ++dti) {
        const int tcv = dti == 0 ? tc0 : (dti == 1 ? tc1 : tc2);
        const int hcv = dti == 0 ? hv0 : (dti == 1 ? hv1 : hv2);
        const int wcv = dti == 0 ? wv0 : (dti == 1 ? wv1 : wv2);
        const int h0d = max(hcv - 4, 0), w0d = max(wcv - 4, 0);
        const float* fb = noisy + (size_t)(tcv * CC) * HW;
        #pragma unroll
        for (int it = 0; it < 4; ++it) {
            const int idx = it * 64 + lane;
            if (idx < 240) {
                const int row = idx >> 4, col = idx & 15;
                const int lcol = col ^ TSW(row);            // logical col at this slot
                const int colm = min(lcol, 14);
                const int off  = min(h0d + row, HH - 1) * WW + min(w0d + colm, WW - 1);
                #pragma unroll
                for (int c = 0; c < CC; ++c)
                    tile[wid][dti][c][row][col] = fb[c * HW + off];
            }
        }
    }

    // --- query row into registers (per-lane i = sub); wq is wave-uniform ---
    float qv[CC][7];
    {
        const int rowq = min(hq + sub, HH - 1);
        const float* qb = noisy + (size_t)(tqi * CC) * HW + (size_t)rowq * WW;
        if (wq <= WW - 8) {
            #pragma unroll
            for (int c = 0; c < CC; ++c) {
                float t[8];
                *(f4u*)&t[0] = *(const f4u*)(qb + c * HW + wq);
                *(f4u*)&t[4] = *(const f4u*)(qb + c * HW + wq + 4);
                #pragma unroll
                for (int j = 0; j < 7; ++j) qv[c][j] = t[j];
            }
        } else {
            #pragma unroll
            for (int c = 0; c < CC; ++c)
                #pragma unroll
                for (int j = 0; j < 7; ++j) qv[c][j] = qb[c * HW + min(wq + j, WW - 1)];
        }
    }
    __builtin_amdgcn_wave_barrier();   // order staging ds_writes before search ds_reads

    // --- search: 4 iterations x 8 groups; group g = (dti,dh), lane sub = i ---
    const float* tb0 = &tile[wid][0][0][0][0];
    #pragma unroll
    for (int it = 0; it < 4; ++it) {
        const int g = it * 8 + (lane >> 3);
        if (g < 27) {
            const int dti = (g >= 18) ? 2 : ((g >= 9) ? 1 : 0);
            const int dh  = g - dti * 9;
            const int hcv = dti == 0 ? hv0 : (dti == 1 ? hv1 : hv2);
            const int wcv = dti == 0 ? wv0 : (dti == 1 ? wv1 : wv2);
            float acc[9];
            #pragma unroll
            for (int dw = 0; dw < 9; ++dw) acc[dw] = 0.f;
            if (sub < PS) {
                if (hcv >= 4 && wcv >= 4) {
                    const int r  = dh + sub;
                    const int sw = TSW(r);
                    const float* tr = tb0 + ((dti * 3 + 0) * 15 + r) * 16;
                    #pragma unroll
                    for (int c = 0; c < CC; ++c) {
                        const float* trc = tr + c * (15 * 16);
                        float tv[16];
                        *(f4a*)&tv[0]  = *(const f4a*)(trc + (0  ^ sw));
                        *(f4a*)&tv[4]  = *(const f4a*)(trc + (4  ^ sw));
                        *(f4a*)&tv[8]  = *(const f4a*)(trc + (8  ^ sw));
                        *(f4a*)&tv[12] = *(const f4a*)(trc + (12 ^ sw));
                        #pragma unroll
                        for (int dw = 0; dw < 9; ++dw) {
                            #pragma unroll
                            for (int j = 0; j < 7; ++j) {
                                const float d = qv[c][j] - tv[dw + j];
                                acc[dw] = fmaf(d, d, acc[dw]);
                            }
                        }
                    }
                } else {
                    // top/left-edge centers: double clamp mapped into the tile
                    const int h0 = max(hcv - 4, 0), w0 = max(wcv - 4, 0);
                    const int hc = min(max(hcv + dh - 4, 0), HH - 1);
                    const int r  = min(hc + sub, HH - 1) - h0;
                    const int sw = TSW(r);
                    const float* tr = tb0 + (dti * 3 * 15 + r) * 16;
                    #pragma unroll
                    for (int c = 0; c < CC; ++c) {
                        const float* trc = tr + c * (15 * 16);
                        #pragma unroll
                        for (int dw = 0; dw < 9; ++dw) {
                            const int wc = min(max(wcv + dw - 4, 0), WW - 1);
                            #pragma unroll
                            for (int j = 0; j < 7; ++j) {
                                const int col = min(wc + j, WW - 1) - w0;
                                const float d = qv[c][j] - trc[col ^ sw];
                                acc[dw] = fmaf(d, d, acc[dw]);
                            }
                        }
                    }
                }
            }
            // sum the 7 patch rows across the 8-lane segment (sub 7 adds 0)
            #pragma unroll
            for (int dw = 0; dw < 9; ++dw) {
                float v = acc[dw];
                v += __shfl_xor(v, 1);
                v += __shfl_xor(v, 2);
                v += __shfl_xor(v, 4);
                acc[dw] = v;
            }
            if (sub == 0) {
                #pragma unroll
                for (int dw = 0; dw < 9; ++dw) dists[wid][g * 9 + dw] = acc[dw];
            }
        }
    }
    __builtin_amdgcn_wave_barrier();   // order dist ds_writes before ds_reads (in-order DS pipe)

    // --- in-register top-k, once per wave (strict <, lowest-index tie-break) ---
    const float* dq = dists[wid];
    float dv[4]; int dn[4];
    #pragma unroll
    for (int kk = 0; kk < 4; ++kk) {
        const int n = lane + kk * 64;
        float v = (n < NOFF) ? dq[n] : INFINITY;
        if (n == SELF_IDX) v = -INFINITY;
        dv[kk] = v; dn[kk] = n;
    }
    int seln[KMAX];
    #pragma unroll
    for (int k = 0; k < KMAX; ++k) {
        float bv = dv[0]; int bi = dn[0];
        #pragma unroll
        for (int kk = 1; kk < 4; ++kk)
            if (dv[kk] < bv || (dv[kk] == bv && dn[kk] < bi)) { bv = dv[kk]; bi = dn[kk]; }
        #pragma unroll
        for (int off = 32; off > 0; off >>= 1) {
            const float ov = __shfl_xor(bv, off);
            const int   oi = __shfl_xor(bi, off);
            if (ov < bv || (ov == bv && oi < bi)) { bv = ov; bi = oi; }
        }
        seln[k] = bi;
        #pragma unroll
        for (int kk = 0; kk < 4; ++kk) if (dn[kk] == bi) dv[kk] = INFINITY;
    }

    // --- refine: deno-query (global) vs noisy (tile LDS), slots 1..k_eff-1 ---
    float part = 0.f;
    const int nref = (k_eff - 1) * 49;
    for (int u = lane; u < nref; u += 64) {
        const int kk = u / 49 + 1;
        const int ij = u - (kk - 1) * 49;
        const int i = ij / 7, j = ij - (ij / 7) * 7;
        int n = seln[1];
        #pragma unroll
        for (int t = 2; t < KMAX; ++t) if (kk == t) n = seln[t];
        const int dti = (n >= 162) ? 2 : (n >= 81 ? 1 : 0);
        const int rr  = n - dti * 81;
        const int dh  = rr / 9;
        const int dw  = rr - dh * 9;
        const int hcv = dti == 0 ? hv0 : (dti == 1 ? hv1 : hv2);
        const int wcv = dti == 0 ? wv0 : (dti == 1 ? wv1 : wv2);
        const int h0  = max(hcv - 4, 0), w0 = max(wcv - 4, 0);
        const int hc  = min(max(hcv + dh - 4, 0), HH - 1);
        const int wc  = min(max(wcv + dw - 4, 0), WW - 1);
        const int row = min(hc + i, HH - 1) - h0;
        const int col = min(wc + j, WW - 1) - w0;
        const int sw  = TSW(row);
        const float* tr = tb0 + (dti * 3 * 15 + row) * 16;
        const int rowq = min(hq + i, HH - 1);
        const int colq = min(wq + j, WW - 1);
        const float* db = deno + (size_t)(tqi * CC) * HW + (size_t)rowq * WW + colq;
        #pragma unroll
        for (int c = 0; c < CC; ++c) {
            const float d = db[c * HW] - tr[c * (15 * 16) + (col ^ sw)];
            part = fmaf(d, d, part);
        }
    }

    #pragma unroll
    for (int off = 32; off > 0; off >>= 1) part += __shfl_xor(part, off);
    if (lane == 0) partial[q] = part;
}

__global__ __launch_bounds__(1024) void dnls_reduce_kernel(
    const float* __restrict__ partial, int n,
    const int* __restrict__ ep_ptr, float* __restrict__ out)
{
    const int tid = threadIdx.x;
    double acc = 0.0;
    for (int i = tid; i < n; i += 1024) acc += (double)partial[i];
    __shared__ double red[1024];
    red[tid] = acc;
    __syncthreads();
    for (int s = 512; s > 0; s >>= 1) {
        if (tid < s) red[tid] += red[tid + s];
        __syncthreads();
    }
    if (tid == 0) {
        const int k_eff = k_eff_from_epoch(ep_ptr[0]);
        out[0] = (float)(red[0] / ((double)n * (double)(k_eff - 1)));
    }
}

extern "C" void kernel_launch(void* const* d_in, const int* in_sizes, int n_in,
                              void* d_out, int out_size, void* d_ws, size_t ws_size,
                              hipStream_t stream) {
    const float* noisy = (const float*)d_in[0];
    const float* deno  = (const float*)d_in[1];
    const float* fflow = (const float*)d_in[2];
    const float* bflow = (const float*)d_in[3];
    const int*   ep    = (const int*)d_in[4];
    float* partial = (float*)d_ws;            // BB*QQ floats = 80 KB
    float* out = (float*)d_out;

    dnls_query_kernel<<<(BB * QQ) / 4, 256, 0, stream>>>(noisy, deno, fflow, bflow, ep, partial);
    dnls_reduce_kernel<<<1, 1024, 0, stream>>>(partial, BB * QQ, ep, out);
}

// Round 7
// 166.360 us; speedup vs baseline: 2.7389x; 1.3808x over previous
//
#include <hip/hip_runtime.h>

#define WS 9
#define PS 7
#define KMAX 10
#define STRIDE0 4
#define NEPOCHS 100
#define BB 1
#define TT 5
#define CC 3
#define HH 256
#define WW 256
#define QQ (TT * 64 * 64)             // 20480
#define NOFF 243
#define SELF_IDX 40                   // (WS/2)*WS + WS/2
#define HW (HH * WW)
#define TSTR 20                       // tile row stride: 80B = b128-aligned

typedef float f4a __attribute__((ext_vector_type(4)));

static __device__ __forceinline__ int k_eff_from_epoch(int ep) {
    int k = (int)((double)KMAX * ((double)(NEPOCHS - ep) / (double)NEPOCHS));
    return k < 2 ? 2 : k;
}

// One query per 256-thread block (R5 skeleton). Staging + search use all 4
// waves; after the post-search barrier, wave 0 alone does top-k + refine +
// output write while waves 1-3 exit (frees their issue slots; no redundant
// top-k, no 3rd barrier). 2 barriers total.
__global__ __launch_bounds__(256) void dnls_query_kernel(
    const float* __restrict__ noisy, const float* __restrict__ deno,
    const float* __restrict__ fflow, const float* __restrict__ bflow,
    const int* __restrict__ ep_ptr, float* __restrict__ partial)
{
    const int q    = blockIdx.x;
    const int tqi  = q >> 12;
    const int r0   = q & 4095;
    const int hq   = (r0 >> 6) * STRIDE0;
    const int wq   = (r0 & 63) * STRIDE0;
    const int tid  = threadIdx.x;
    const int lane = tid & 63;
    const int k_eff = k_eff_from_epoch(ep_ptr[0]);

    __shared__ float tile[3][CC][15][TSTR];   // 10.8 KB
    __shared__ float qpat[CC][PS][8];         // noisy query patch (rows b128-aligned)
    __shared__ float dpat[CC][PS][8];         // deno query patch
    __shared__ float dists[256];

    // --- centers (every thread; flow loads are wave-uniform -> broadcast) ---
    const size_t bfo = (size_t)(tqi * 2) * HW + (size_t)hq * WW + wq;
    const int ifdx = (int)rintf(fflow[bfo]);
    const int ifdy = (int)rintf(fflow[bfo + HW]);
    const int ibdx = (int)rintf(bflow[bfo]);
    const int ibdy = (int)rintf(bflow[bfo + HW]);
    const int tcA[3] = { tqi, max(tqi - 1, 0), min(tqi + 1, TT - 1) };
    const int hvA[3] = { hq, min(max(hq + ibdy, 0), HH - 1), min(max(hq + ifdy, 0), HH - 1) };
    const int wvA[3] = { wq, min(max(wq + ibdx, 0), WW - 1), min(max(wq + ifdx, 0), WW - 1) };

    // --- stage tiles: 9 unrolled (dti,c) planes, 225 elems each, clamps baked in ---
    #pragma unroll
    for (int dtc = 0; dtc < 9; ++dtc) {
        const int dti = dtc / 3, c = dtc % 3;          // compile-time
        if (tid < 225) {
            const int row = tid / 15;
            const int col = tid - row * 15;
            const int h0 = max(hvA[dti] - 4, 0);
            const int w0 = max(wvA[dti] - 4, 0);
            const float* src = noisy + (size_t)(tcA[dti] * CC + c) * HW;
            tile[dti][c][row][col] = src[min(h0 + row, HH - 1) * WW + min(w0 + col, WW - 1)];
        }
    }
    // --- stage query patches (clamps baked in) ---
    if (tid < CC * PS * PS) {
        const int c = tid / 49, ij = tid - c * 49, i = ij / 7, j = ij - (ij / 7) * 7;
        const size_t idx = (size_t)(tqi * CC + c) * HW + min(hq + i, HH - 1) * WW + min(wq + j, WW - 1);
        qpat[c][i][j] = noisy[idx];
        dpat[c][i][j] = deno[idx];
    }
    __syncthreads();

    // --- search: group g=(dti,dh), sub = patch row i (sub==7 idle) ---
    {
        const int g = tid >> 3, sub = tid & 7;
        if (g < 27) {
            const int dti = (g >= 18) ? 2 : (g >= 9 ? 1 : 0);
            const int dh  = g - 9 * dti;
            const int hcv = hvA[dti], wcv = wvA[dti];
            float acc[9];
            #pragma unroll
            for (int dw = 0; dw < 9; ++dw) acc[dw] = 0.f;
            if (sub < PS) {
                const int i = sub;
                if (hcv >= 4 && wcv >= 4) {
                    // fast path: staged clamps are exact; r = dh+i, cols = dw+j
                    const int r = dh + i;
                    #pragma unroll
                    for (int c = 0; c < CC; ++c) {
                        float qv[8], tv[16];
                        *(f4a*)&qv[0]  = *(const f4a*)&qpat[c][i][0];
                        *(f4a*)&qv[4]  = *(const f4a*)&qpat[c][i][4];
                        *(f4a*)&tv[0]  = *(const f4a*)&tile[dti][c][r][0];
                        *(f4a*)&tv[4]  = *(const f4a*)&tile[dti][c][r][4];
                        *(f4a*)&tv[8]  = *(const f4a*)&tile[dti][c][r][8];
                        *(f4a*)&tv[12] = *(const f4a*)&tile[dti][c][r][12];
                        #pragma unroll
                        for (int dw = 0; dw < 9; ++dw) {
                            #pragma unroll
                            for (int j = 0; j < 7; ++j) {
                                const float d = qv[j] - tv[dw + j];
                                acc[dw] = fmaf(d, d, acc[dw]);
                            }
                        }
                    }
                } else {
                    // top/left-edge centers: double clamp mapped into the tile
                    const int h0 = max(hcv - 4, 0), w0 = max(wcv - 4, 0);
                    const int hc = min(max(hcv + dh - 4, 0), HH - 1);
                    const int r  = min(hc + i, HH - 1) - h0;
                    #pragma unroll
                    for (int c = 0; c < CC; ++c) {
                        float qv[8];
                        *(f4a*)&qv[0] = *(const f4a*)&qpat[c][i][0];
                        *(f4a*)&qv[4] = *(const f4a*)&qpat[c][i][4];
                        #pragma unroll
                        for (int dw = 0; dw < 9; ++dw) {
                            const int wc = min(max(wcv + dw - 4, 0), WW - 1);
                            #pragma unroll
                            for (int j = 0; j < 7; ++j) {
                                const int col = min(wc + j, WW - 1) - w0;
                                const float d = qv[j] - tile[dti][c][r][col];
                                acc[dw] = fmaf(d, d, acc[dw]);
                            }
                        }
                    }
                }
            }
            // sum the 7 rows across the 8-lane segment
            #pragma unroll
            for (int dw = 0; dw < 9; ++dw) {
                float v = acc[dw];
                v += __shfl_xor(v, 1);
                v += __shfl_xor(v, 2);
                v += __shfl_xor(v, 4);
                acc[dw] = v;
            }
            if (sub == 0) {
                #pragma unroll
                for (int dw = 0; dw < 9; ++dw) dists[g * 9 + dw] = acc[dw];
            }
        }
    }
    __syncthreads();

    if (tid >= 64) return;   // waves 1-3 done; wave 0 finishes the query

    // --- in-register top-k, wave 0 only (strict <, lowest-index tie-break) ---
    float dv[4]; int dn[4];
    #pragma unroll
    for (int kk = 0; kk < 4; ++kk) {
        const int n = lane + kk * 64;
        float v = (n < NOFF) ? dists[n] : INFINITY;
        if (n == SELF_IDX) v = -INFINITY;
        dv[kk] = v; dn[kk] = n;
    }
    int seln[KMAX];
    #pragma unroll
    for (int k = 0; k < KMAX; ++k) {
        float bv = dv[0]; int bi = dn[0];
        #pragma unroll
        for (int kk = 1; kk < 4; ++kk)
            if (dv[kk] < bv || (dv[kk] == bv && dn[kk] < bi)) { bv = dv[kk]; bi = dn[kk]; }
        #pragma unroll
        for (int off = 32; off > 0; off >>= 1) {
            const float ov = __shfl_xor(bv, off);
            const int   oi = __shfl_xor(bi, off);
            if (ov < bv || (ov == bv && oi < bi)) { bv = ov; bi = oi; }
        }
        seln[k] = bi;
        #pragma unroll
        for (int kk = 0; kk < 4; ++kk) if (dn[kk] == bi) dv[kk] = INFINITY;
    }

    // --- refine: deno-query vs noisy at selected positions (slots 1..k_eff-1) ---
    float part = 0.f;
    const int nref = (k_eff - 1) * 49;
    for (int u = lane; u < nref; u += 64) {
        const int kk = u / 49 + 1;
        const int ij = u - (kk - 1) * 49;
        const int i = ij / 7, j = ij - (ij / 7) * 7;
        int n = seln[1];
        #pragma unroll
        for (int t = 2; t < KMAX; ++t) if (kk == t) n = seln[t];
        const int dti = (n >= 162) ? 2 : (n >= 81 ? 1 : 0);
        const int rr  = n - dti * 81;
        const int dh  = rr / 9;
        const int dw  = rr - dh * 9;
        const int hcv = hvA[dti], wcv = wvA[dti];
        const int h0  = max(hcv - 4, 0), w0 = max(wcv - 4, 0);
        const int hc  = min(max(hcv + dh - 4, 0), HH - 1);
        const int wc  = min(max(wcv + dw - 4, 0), WW - 1);
        const int row = min(hc + i, HH - 1) - h0;
        const int col = min(wc + j, WW - 1) - w0;
        #pragma unroll
        for (int c = 0; c < CC; ++c) {
            const float d = dpat[c][i][j] - tile[dti][c][row][col];
            part = fmaf(d, d, part);
        }
    }

    #pragma unroll
    for (int off = 32; off > 0; off >>= 1) part += __shfl_xor(part, off);
    if (lane == 0) partial[q] = part;
}

__global__ __launch_bounds__(1024) void dnls_reduce_kernel(
    const float* __restrict__ partial, int n,
    const int* __restrict__ ep_ptr, float* __restrict__ out)
{
    const int tid = threadIdx.x;
    double acc = 0.0;
    for (int i = tid; i < n; i += 1024) acc += (double)partial[i];
    __shared__ double red[1024];
    red[tid] = acc;
    __syncthreads();
    for (int s = 512; s > 0; s >>= 1) {
        if (tid < s) red[tid] += red[tid + s];
        __syncthreads();
    }
    if (tid == 0) {
        const int k_eff = k_eff_from_epoch(ep_ptr[0]);
        out[0] = (float)(red[0] / ((double)n * (double)(k_eff - 1)));
    }
}

extern "C" void kernel_launch(void* const* d_in, const int* in_sizes, int n_in,
                              void* d_out, int out_size, void* d_ws, size_t ws_size,
                              hipStream_t stream) {
    const float* noisy = (const float*)d_in[0];
    const float* deno  = (const float*)d_in[1];
    const float* fflow = (const float*)d_in[2];
    const float* bflow = (const float*)d_in[3];
    const int*   ep    = (const int*)d_in[4];
    float* partial = (float*)d_ws;            // BB*QQ floats = 80 KB
    float* out = (float*)d_out;

    dnls_query_kernel<<<BB * QQ, 256, 0, stream>>>(noisy, deno, fflow, bflow, ep, partial);
    dnls_reduce_kernel<<<1, 1024, 0, stream>>>(partial, BB * QQ, ep, out);
}